// Round 7
// baseline (804.041 us; speedup 1.0000x reference)
//
#include <hip/hip_runtime.h>

#define N_NODES 50000
#define N_EDGES 800000
#define FEAT 128
#define HID 256
#define N_GRAPHS 64
#define NB_SCAN ((N_NODES + 255) / 256)

typedef float floatx4 __attribute__((ext_vector_type(4)));
typedef _Float16 half4_t __attribute__((ext_vector_type(4)));
typedef _Float16 half8_t __attribute__((ext_vector_type(8)));

// ---------------- graph preprocessing ----------------

__global__ void hist_kernel(const int* __restrict__ dst, int* __restrict__ cnt, int e) {
  int i = blockIdx.x * blockDim.x + threadIdx.x;
  if (i < e) atomicAdd(&cnt[dst[i]], 1);
}

__global__ __launch_bounds__(256) void scan1_kernel(const int* __restrict__ cnt,
                                                    float* __restrict__ dinv,
                                                    int* __restrict__ bsum, int n) {
  __shared__ int sh[256];
  int i = blockIdx.x * 256 + threadIdx.x;
  int c = (i < n) ? cnt[i] : 0;
  if (i < n) dinv[i] = 1.0f / sqrtf((float)c + 1.0f);
  sh[threadIdx.x] = c;
  __syncthreads();
  for (int off = 128; off > 0; off >>= 1) {
    if (threadIdx.x < off) sh[threadIdx.x] += sh[threadIdx.x + off];
    __syncthreads();
  }
  if (threadIdx.x == 0) bsum[blockIdx.x] = sh[0];
}

__global__ __launch_bounds__(256) void scan2_kernel(const int* __restrict__ bsum,
                                                    int* __restrict__ boff,
                                                    int* __restrict__ rowptr) {
  __shared__ int sh[256];
  int t = threadIdx.x;
  int v = (t < NB_SCAN) ? bsum[t] : 0;
  sh[t] = v;
  __syncthreads();
  for (int off = 1; off < 256; off <<= 1) {
    int u = (t >= off) ? sh[t - off] : 0;
    __syncthreads();
    sh[t] += u;
    __syncthreads();
  }
  if (t < NB_SCAN) boff[t] = (t == 0) ? 0 : sh[t - 1];
  if (t == 255) rowptr[N_NODES] = sh[255];
}

__global__ __launch_bounds__(256) void scan3_kernel(const int* __restrict__ cnt,
                                                    const int* __restrict__ boff,
                                                    int* __restrict__ rowptr, int n) {
  __shared__ int sh[256];
  int i = blockIdx.x * 256 + threadIdx.x;
  int c = (i < n) ? cnt[i] : 0;
  sh[threadIdx.x] = c;
  __syncthreads();
  for (int off = 1; off < 256; off <<= 1) {
    int u = (threadIdx.x >= off) ? sh[threadIdx.x - off] : 0;
    __syncthreads();
    sh[threadIdx.x] += u;
    __syncthreads();
  }
  if (i < n) rowptr[i] = boff[blockIdx.x] + sh[threadIdx.x] - c;
}

__global__ void place_kernel(const int* __restrict__ dst, const int* __restrict__ rowptr,
                             int* __restrict__ cursor, int* __restrict__ csr, int e) {
  int i = blockIdx.x * blockDim.x + threadIdx.x;
  if (i < e) {
    int d = dst[i];
    int slot = rowptr[d] + atomicAdd(&cursor[d], 1);
    csr[slot] = i;
  }
}

// one wave per row: bitonic sort of edge ids (canonical order), then csr[slot] = src
__global__ __launch_bounds__(256) void sortrow_kernel(
    int* __restrict__ csr, const int* __restrict__ rowptr,
    const int* __restrict__ src, int n) {
  int wid = (blockIdx.x * 256 + threadIdx.x) >> 6;
  int lane = threadIdx.x & 63;
  if (wid >= n) return;
  int beg = rowptr[wid], len = rowptr[wid + 1] - beg;
  if (len <= 64) {
    int v = (lane < len) ? csr[beg + lane] : 0x7fffffff;
    #pragma unroll
    for (int k = 2; k <= 64; k <<= 1) {
      #pragma unroll
      for (int j = k >> 1; j >= 1; j >>= 1) {
        int other = __shfl_xor(v, j);
        int mn = min(v, other), mx = max(v, other);
        bool up = (lane & k) == 0;
        v = (((lane & j) == 0) == up) ? mn : mx;
      }
    }
    if (lane < len) csr[beg + lane] = src[v];
  } else if (lane == 0) {           // unreachable in practice; scratch-free fallback
    for (int a = 0; a < len; ++a)
      for (int b = a + 1; b < len; ++b) {
        int xa = csr[beg + a], xb = csr[beg + b];
        if (xb < xa) { csr[beg + a] = xb; csr[beg + b] = xa; }
      }
    for (int a = 0; a < len; ++a) csr[beg + a] = src[csr[beg + a]];
  }
}

// ---------------- weight conversion ----------------
__global__ void cvtw_kernel(const float* __restrict__ W0, _Float16* __restrict__ W0t,
                            const float* __restrict__ W1, _Float16* __restrict__ W1t,
                            const float* __restrict__ W2, _Float16* __restrict__ W2at) {
  int idx = blockIdx.x * blockDim.x + threadIdx.x;
  if (idx < FEAT * 256) {
    int c = idx / FEAT, k = idx - c * FEAT;
    W0t[idx] = (_Float16)W0[k * 256 + c];
    return;
  }
  idx -= FEAT * 256;
  if (idx < HID * 256) {
    int c = idx / HID, k = idx - c * HID;
    W1t[idx] = (_Float16)W1[k * 256 + c];
    return;
  }
  idx -= HID * 256;
  if (idx < HID * 256) {
    int c = idx / HID, k = idx - c * HID;
    W2at[idx] = (_Float16)W2[k * 256 + c];
  }
}

// ---------------- XCD-sliced aggregation (f16 features) ----------------
// slice = blockIdx&7 -> XCD; each L2 holds one 32-feature slice (3.2 MB).
template <int F>
__global__ __launch_bounds__(256) void agg_slice_kernel(
    const _Float16* __restrict__ T, const int* __restrict__ csr,
    const int* __restrict__ rowptr, const float* __restrict__ dinv,
    _Float16* __restrict__ out, int n) {
  constexpr int RST = F / 8;            // half8 chunks per row
  constexpr int LPR = RST / 8;          // lanes per row (8 slices)
  constexpr int RPB = 256 / LPR;
  int slice = blockIdx.x & 7;
  int grp = blockIdx.x >> 3;
  int li = threadIdx.x & (LPR - 1);
  int d = grp * RPB + threadIdx.x / LPR;
  if (d >= n) return;
  const half8_t* Tv = (const half8_t*)T;
  int cbase = slice * LPR + li;
  int beg = rowptr[d], end = rowptr[d + 1];
  float acc[8];
  #pragma unroll
  for (int e = 0; e < 8; ++e) acc[e] = 0.f;
  int j = beg;
  for (; j + 4 <= end; j += 4) {
    int s0 = __builtin_nontemporal_load(&csr[j]);
    int s1 = __builtin_nontemporal_load(&csr[j + 1]);
    int s2 = __builtin_nontemporal_load(&csr[j + 2]);
    int s3 = __builtin_nontemporal_load(&csr[j + 3]);
    float w0 = dinv[s0], w1 = dinv[s1], w2 = dinv[s2], w3 = dinv[s3];
    half8_t v0 = Tv[(size_t)s0 * RST + cbase];
    half8_t v1 = Tv[(size_t)s1 * RST + cbase];
    half8_t v2 = Tv[(size_t)s2 * RST + cbase];
    half8_t v3 = Tv[(size_t)s3 * RST + cbase];
    #pragma unroll
    for (int e = 0; e < 8; ++e)
      acc[e] += w0 * (float)v0[e] + w1 * (float)v1[e] + w2 * (float)v2[e] + w3 * (float)v3[e];
  }
  for (; j < end; ++j) {
    int s0 = __builtin_nontemporal_load(&csr[j]);
    float w0 = dinv[s0];
    half8_t v0 = Tv[(size_t)s0 * RST + cbase];
    #pragma unroll
    for (int e = 0; e < 8; ++e) acc[e] += w0 * (float)v0[e];
  }
  float di = dinv[d];
  half8_t vs = Tv[(size_t)d * RST + cbase];
  half8_t o;
  #pragma unroll
  for (int e = 0; e < 8; ++e)
    o[e] = (_Float16)(acc[e] * di + (float)vs[e] * di * di);
  __builtin_nontemporal_store(o, &((half8_t*)out)[(size_t)d * RST + cbase]);
}

// ---- conv0 agg: reads f32 x directly (16-feat f32 slices), writes f16 [n][128]
__global__ __launch_bounds__(256) void agg0_slice_kernel(
    const float* __restrict__ x, const int* __restrict__ csr,
    const int* __restrict__ rowptr, const float* __restrict__ dinv,
    _Float16* __restrict__ out, int n) {
  constexpr int LPR = 4;                // 4 lanes x float4 = 16 feats
  constexpr int RPB = 64;
  int slice = blockIdx.x & 7;
  int grp = blockIdx.x >> 3;
  int li = threadIdx.x & 3;
  int d = grp * RPB + (threadIdx.x >> 2);
  if (d >= n) return;
  const floatx4* Xv = (const floatx4*)x;   // 32 chunks/row
  int cbase = slice * 4 + li;
  int beg = rowptr[d], end = rowptr[d + 1];
  float acc[4] = {0.f, 0.f, 0.f, 0.f};
  int j = beg;
  for (; j + 4 <= end; j += 4) {
    int s0 = __builtin_nontemporal_load(&csr[j]);
    int s1 = __builtin_nontemporal_load(&csr[j + 1]);
    int s2 = __builtin_nontemporal_load(&csr[j + 2]);
    int s3 = __builtin_nontemporal_load(&csr[j + 3]);
    float w0 = dinv[s0], w1 = dinv[s1], w2 = dinv[s2], w3 = dinv[s3];
    floatx4 v0 = Xv[(size_t)s0 * 32 + cbase];
    floatx4 v1 = Xv[(size_t)s1 * 32 + cbase];
    floatx4 v2 = Xv[(size_t)s2 * 32 + cbase];
    floatx4 v3 = Xv[(size_t)s3 * 32 + cbase];
    #pragma unroll
    for (int e = 0; e < 4; ++e)
      acc[e] += w0 * v0[e] + w1 * v1[e] + w2 * v2[e] + w3 * v3[e];
  }
  for (; j < end; ++j) {
    int s0 = __builtin_nontemporal_load(&csr[j]);
    float w0 = dinv[s0];
    floatx4 v0 = Xv[(size_t)s0 * 32 + cbase];
    #pragma unroll
    for (int e = 0; e < 4; ++e) acc[e] += w0 * v0[e];
  }
  float di = dinv[d];
  floatx4 vs = Xv[(size_t)d * 32 + cbase];
  half4_t o;
  #pragma unroll
  for (int e = 0; e < 4; ++e)
    o[e] = (_Float16)(acc[e] * di + vs[e] * di * di);
  __builtin_nontemporal_store(o, &((half4_t*)out)[(size_t)d * 32 + cbase]);
}

// ---- sliced agg + bias + relu + dot(W3) -> 8 partials per node
__global__ __launch_bounds__(256) void agg_dot_slice_kernel(
    const _Float16* __restrict__ T, const int* __restrict__ csr,
    const int* __restrict__ rowptr, const float* __restrict__ dinv,
    const float* __restrict__ bias, const float* __restrict__ W3,
    float* __restrict__ t3part, int n) {
  constexpr int RST = 32, LPR = 4, RPB = 64;
  int slice = blockIdx.x & 7;
  int grp = blockIdx.x >> 3;
  int li = threadIdx.x & 3;
  int d = grp * RPB + (threadIdx.x >> 2);
  if (d >= n) return;
  const half8_t* Tv = (const half8_t*)T;
  int cbase = slice * LPR + li;
  int beg = rowptr[d], end = rowptr[d + 1];
  float acc[8];
  #pragma unroll
  for (int e = 0; e < 8; ++e) acc[e] = 0.f;
  int j = beg;
  for (; j + 4 <= end; j += 4) {
    int s0 = __builtin_nontemporal_load(&csr[j]);
    int s1 = __builtin_nontemporal_load(&csr[j + 1]);
    int s2 = __builtin_nontemporal_load(&csr[j + 2]);
    int s3 = __builtin_nontemporal_load(&csr[j + 3]);
    float w0 = dinv[s0], w1 = dinv[s1], w2 = dinv[s2], w3 = dinv[s3];
    half8_t v0 = Tv[(size_t)s0 * RST + cbase];
    half8_t v1 = Tv[(size_t)s1 * RST + cbase];
    half8_t v2 = Tv[(size_t)s2 * RST + cbase];
    half8_t v3 = Tv[(size_t)s3 * RST + cbase];
    #pragma unroll
    for (int e = 0; e < 8; ++e)
      acc[e] += w0 * (float)v0[e] + w1 * (float)v1[e] + w2 * (float)v2[e] + w3 * (float)v3[e];
  }
  for (; j < end; ++j) {
    int s0 = __builtin_nontemporal_load(&csr[j]);
    float w0 = dinv[s0];
    half8_t v0 = Tv[(size_t)s0 * RST + cbase];
    #pragma unroll
    for (int e = 0; e < 8; ++e) acc[e] += w0 * (float)v0[e];
  }
  float di = dinv[d];
  half8_t vs = Tv[(size_t)d * RST + cbase];
  int f0 = slice * 32 + li * 8;
  float s = 0.f;
  #pragma unroll
  for (int e = 0; e < 8; ++e) {
    float v = acc[e] * di + (float)vs[e] * di * di + bias[f0 + e];
    v = fmaxf(v, 0.f);
    s += v * W3[f0 + e];
  }
  s += __shfl_xor(s, 1);
  s += __shfl_xor(s, 2);
  if (li == 0) t3part[(size_t)d * 8 + slice] = s;
}

__global__ void combine_kernel(const float* __restrict__ t3part, float* __restrict__ t3, int n) {
  int d = blockIdx.x * blockDim.x + threadIdx.x;
  if (d >= n) return;
  float s = 0.f;
  #pragma unroll
  for (int k = 0; k < 8; ++k) s += t3part[(size_t)d * 8 + k];
  t3[d] = s;
}

// ---------------- tiled MFMA GEMM (optional fused graph-max-pool) ----------------
template <int K, bool BIAS, bool RELU, bool GIADD, bool POOL>
__global__ __launch_bounds__(256) void gemm_tile(
    const _Float16* __restrict__ A, const _Float16* __restrict__ Bt,
    const float* __restrict__ bias, const float* __restrict__ gi2,
    const int* __restrict__ batch, _Float16* __restrict__ C,
    int* __restrict__ poolI, int nrows) {
  constexpr int ROWB = K * 2;
  constexpr int CPR = K / 8;
  __shared__ _Float16 smem[128 * K];
  __shared__ int Pred[2][HID];
  char* sb = (char*)smem;
  int tid = threadIdx.x;
  int row0 = blockIdx.x * 128;
  if (POOL) { Pred[0][tid] = 0; Pred[1][tid] = 0; }

  #pragma unroll
  for (int it = 0; it < K / 16; ++it) {
    int e = it * 256 + tid;
    int r = e / CPR;
    int cof = (e - r * CPR) * 16;
    int grow = min(row0 + r, nrows - 1);
    half8_t v = *(const half8_t*)(A + (size_t)grow * K + cof / 2);
    *(half8_t*)&sb[r * ROWB + (cof ^ ((r & 7) << 4))] = v;
  }
  __syncthreads();

  int lane = tid & 63, wv = tid >> 6;
  int rlo = lane & 15, khi = lane >> 4;
  int cw0 = wv * 64;
  floatx4 acc[8][4];
  #pragma unroll
  for (int h = 0; h < 8; ++h)
    #pragma unroll
    for (int g = 0; g < 4; ++g)
      { acc[h][g][0] = 0.f; acc[h][g][1] = 0.f; acc[h][g][2] = 0.f; acc[h][g][3] = 0.f; }

  for (int kc = 0; kc < K; kc += 32) {
    int kbyte = kc * 2 + khi * 16;
    half8_t xa[8];
    #pragma unroll
    for (int h = 0; h < 8; ++h) {
      int r = h * 16 + rlo;
      xa[h] = *(half8_t*)&sb[r * ROWB + (kbyte ^ ((r & 7) << 4))];
    }
    #pragma unroll
    for (int g = 0; g < 4; ++g) {
      half8_t wb = *(const half8_t*)(Bt + (size_t)(cw0 + g * 16 + rlo) * K + kc + khi * 8);
      #pragma unroll
      for (int h = 0; h < 8; ++h)
        acc[h][g] = __builtin_amdgcn_mfma_f32_16x16x32_f16(wb, xa[h], acc[h][g], 0, 0, 0);
    }
  }

  int g0 = 0;
  if (POOL) g0 = batch[min(row0, nrows - 1)];
  bool rvalid[8]; int rwh[8];
  #pragma unroll
  for (int h = 0; h < 8; ++h) {
    int crow = row0 + h * 16 + rlo;
    rvalid[h] = crow < nrows;
    rwh[h] = (POOL && rvalid[h]) ? (batch[crow] != g0) : 0;
  }

  #pragma unroll
  for (int g = 0; g < 4; ++g) {
    int c0 = cw0 + g * 16 + khi * 4;
    floatx4 pm0 = {0.f, 0.f, 0.f, 0.f}, pm1 = {0.f, 0.f, 0.f, 0.f};
    #pragma unroll
    for (int h = 0; h < 8; ++h) {
      if (!rvalid[h]) continue;
      int crow = row0 + h * 16 + rlo;
      floatx4 v = acc[h][g];
      if (BIAS) v += *(const floatx4*)(bias + c0);
      if (GIADD) v += *(const floatx4*)(gi2 + (size_t)batch[crow] * HID + c0);
      if (RELU) {
        v[0] = fmaxf(v[0], 0.f); v[1] = fmaxf(v[1], 0.f);
        v[2] = fmaxf(v[2], 0.f); v[3] = fmaxf(v[3], 0.f);
      }
      if (POOL) {
        if (rwh[h]) { pm1[0] = fmaxf(pm1[0], v[0]); pm1[1] = fmaxf(pm1[1], v[1]);
                      pm1[2] = fmaxf(pm1[2], v[2]); pm1[3] = fmaxf(pm1[3], v[3]); }
        else        { pm0[0] = fmaxf(pm0[0], v[0]); pm0[1] = fmaxf(pm0[1], v[1]);
                      pm0[2] = fmaxf(pm0[2], v[2]); pm0[3] = fmaxf(pm0[3], v[3]); }
      }
      half4_t hv;
      hv[0] = (_Float16)v[0]; hv[1] = (_Float16)v[1];
      hv[2] = (_Float16)v[2]; hv[3] = (_Float16)v[3];
      *(half4_t*)(C + (size_t)crow * HID + c0) = hv;
    }
    if (POOL) {
      #pragma unroll
      for (int e = 0; e < 4; ++e) {
        if (pm0[e] > 0.f) atomicMax(&Pred[0][c0 + e], __float_as_int(pm0[e]));
        if (pm1[e] > 0.f) atomicMax(&Pred[1][c0 + e], __float_as_int(pm1[e]));
      }
    }
  }

  if (POOL) {
    __syncthreads();
    int glast = batch[min(row0 + 127, nrows - 1)];
    atomicMax(&poolI[g0 * HID + tid], Pred[0][tid]);
    if (glast != g0) atomicMax(&poolI[glast * HID + tid], Pred[1][tid]);
  }
}

// ---------------- pooled -> fc1 -> @W2[256:512] ----------------
__global__ __launch_bounds__(256) void pool2_kernel(const int* __restrict__ poolI,
                                                    const float* __restrict__ Wf,
                                                    const float* __restrict__ bf,
                                                    const float* __restrict__ W2,
                                                    float* __restrict__ gi2) {
  __shared__ float P[HID];
  __shared__ float GI[HID];
  int g = blockIdx.x;
  int c = threadIdx.x;
  P[c] = __int_as_float(poolI[g * HID + c]);
  __syncthreads();
  float a = 0.f;
  for (int k = 0; k < HID; ++k) a += P[k] * Wf[k * HID + c];
  GI[c] = a + bf[c];
  __syncthreads();
  float a2 = 0.f;
  for (int k = 0; k < HID; ++k) a2 += GI[k] * W2[(HID + k) * HID + c];
  gi2[g * HID + c] = a2;
}

__global__ void final_kernel(const float* __restrict__ t3, const int* __restrict__ csr,
                             const int* __restrict__ rowptr, const float* __restrict__ dinv,
                             const float* __restrict__ b3, float* __restrict__ out, int n) {
  int d = blockIdx.x * blockDim.x + threadIdx.x;
  if (d >= n) return;
  float acc = 0.f;
  int beg = rowptr[d], end = rowptr[d + 1];
  for (int j = beg; j < end; ++j) {
    int s = csr[j];
    acc += dinv[s] * t3[s];
  }
  float di = dinv[d];
  out[d] = acc * di + t3[d] * di * di + b3[0];
}

// ---------------- launcher ----------------

extern "C" void kernel_launch(void* const* d_in, const int* in_sizes, int n_in,
                              void* d_out, int out_size, void* d_ws, size_t ws_size,
                              hipStream_t stream) {
  const float* x   = (const float*)d_in[0];
  const int* src   = (const int*)d_in[1];
  const int* dst   = (const int*)d_in[2];
  const int* batch = (const int*)d_in[3];
  const float* W0 = (const float*)d_in[4];
  const float* b0 = (const float*)d_in[5];
  const float* Wf = (const float*)d_in[6];
  const float* bf = (const float*)d_in[7];
  const float* W1 = (const float*)d_in[8];
  const float* b1 = (const float*)d_in[9];
  const float* W2 = (const float*)d_in[10];
  const float* b2 = (const float*)d_in[11];
  const float* W3 = (const float*)d_in[12];
  const float* b3 = (const float*)d_in[13];
  float* out = (float*)d_out;

  char* p = (char*)d_ws;
  auto alloc = [&](size_t bytes) { char* q = p; p += (bytes + 255) & ~(size_t)255; return q; };
  _Float16* hA   = (_Float16*)alloc((size_t)N_NODES * HID * 2);
  _Float16* hB   = (_Float16*)alloc((size_t)N_NODES * HID * 2);
  _Float16* W0t  = (_Float16*)alloc((size_t)HID * FEAT * 2);
  _Float16* W1t  = (_Float16*)alloc((size_t)HID * HID * 2);
  _Float16* W2at = (_Float16*)alloc((size_t)HID * HID * 2);
  int*   cnt    = (int*)alloc((size_t)N_NODES * 4);
  int*   rowptr = (int*)alloc((size_t)(N_NODES + 1) * 4);
  int*   cursor = (int*)alloc((size_t)N_NODES * 4);
  int*   csr    = (int*)alloc((size_t)N_EDGES * 4);
  float* dinv   = (float*)alloc((size_t)N_NODES * 4);
  int*   bsum   = (int*)alloc(NB_SCAN * 4);
  int*   boff   = (int*)alloc(NB_SCAN * 4);
  int*   poolI  = (int*)alloc((size_t)N_GRAPHS * HID * 4);
  float* gi2    = (float*)alloc((size_t)N_GRAPHS * HID * 4);
  float* t3part = (float*)alloc((size_t)N_NODES * 8 * 4);
  float* t3     = (float*)alloc((size_t)N_NODES * 4);

  hipMemsetAsync(cnt, 0, (size_t)N_NODES * 4, stream);
  hipMemsetAsync(cursor, 0, (size_t)N_NODES * 4, stream);
  hipMemsetAsync(poolI, 0, (size_t)N_GRAPHS * HID * 4, stream);

  int eb = (N_EDGES + 255) / 256;
  int nb = NB_SCAN;

  cvtw_kernel<<<((FEAT + 2 * HID) * 256 + 255) / 256, 256, 0, stream>>>(W0, W0t, W1, W1t, W2, W2at);

  hist_kernel<<<eb, 256, 0, stream>>>(dst, cnt, N_EDGES);
  scan1_kernel<<<nb, 256, 0, stream>>>(cnt, dinv, bsum, N_NODES);
  scan2_kernel<<<1, 256, 0, stream>>>(bsum, boff, rowptr);
  scan3_kernel<<<nb, 256, 0, stream>>>(cnt, boff, rowptr, N_NODES);
  place_kernel<<<eb, 256, 0, stream>>>(dst, rowptr, cursor, csr, N_EDGES);
  sortrow_kernel<<<(N_NODES * 64 + 255) / 256, 256, 0, stream>>>(csr, rowptr, src, N_NODES);

  int gb = (N_NODES + 127) / 128;
  int sb64 = 8 * ((N_NODES + 63) / 64);     // sliced grids: 8 slices x node-groups

  // conv0: agg(x f32, sliced) -> hA[n][128] f16 ; GEMM (+fused pool) -> hB
  agg0_slice_kernel<<<sb64, 256, 0, stream>>>(x, csr, rowptr, dinv, hA, N_NODES);
  gemm_tile<FEAT, true, true, false, true><<<gb, 256, 0, stream>>>(hA, W0t, b0, nullptr, batch, hB, poolI, N_NODES);

  // gi2 = (pooled @ Wf + bf) @ W2[256:512]
  pool2_kernel<<<N_GRAPHS, 256, 0, stream>>>(poolI, Wf, bf, W2, gi2);

  // conv1 #1
  agg_slice_kernel<HID><<<sb64, 256, 0, stream>>>(hB, csr, rowptr, dinv, hA, N_NODES);
  gemm_tile<HID, true, true, false, false><<<gb, 256, 0, stream>>>(hA, W1t, b1, nullptr, nullptr, hB, nullptr, N_NODES);

  // conv1 #2
  agg_slice_kernel<HID><<<sb64, 256, 0, stream>>>(hB, csr, rowptr, dinv, hA, N_NODES);
  gemm_tile<HID, true, true, false, false><<<gb, 256, 0, stream>>>(hA, W1t, b1, nullptr, nullptr, hB, nullptr, N_NODES);

  // conv2: T2 = loc2@W2a + gi2[batch] -> hA ; sliced agg+bias+relu+dot(W3) -> t3part
  gemm_tile<HID, false, false, true, false><<<gb, 256, 0, stream>>>(hB, W2at, nullptr, gi2, batch, hA, nullptr, N_NODES);
  agg_dot_slice_kernel<<<sb64, 256, 0, stream>>>(hA, csr, rowptr, dinv, b2, W3, t3part, N_NODES);
  combine_kernel<<<(N_NODES + 255) / 256, 256, 0, stream>>>(t3part, t3, N_NODES);

  // conv3 aggregation (scalar)
  final_kernel<<<(N_NODES + 255) / 256, 256, 0, stream>>>(t3, csr, rowptr, dinv, b3, out, N_NODES);
}

// Round 8
// 484.817 us; speedup vs baseline: 1.6584x; 1.6584x over previous
//
#include <hip/hip_runtime.h>

#define N_NODES 50000
#define N_EDGES 800000
#define FEAT 128
#define HID 256
#define N_GRAPHS 64
#define NB_SCAN ((N_NODES + 255) / 256)

typedef float floatx4 __attribute__((ext_vector_type(4)));
typedef _Float16 half4_t __attribute__((ext_vector_type(4)));
typedef _Float16 half8_t __attribute__((ext_vector_type(8)));

// ---------------- graph preprocessing ----------------

__global__ void hist_kernel(const int* __restrict__ dst, int* __restrict__ cnt, int e) {
  int i = blockIdx.x * blockDim.x + threadIdx.x;
  if (i < e) atomicAdd(&cnt[dst[i]], 1);
}

__global__ __launch_bounds__(256) void scan1_kernel(const int* __restrict__ cnt,
                                                    float* __restrict__ dinv,
                                                    int* __restrict__ bsum, int n) {
  __shared__ int sh[256];
  int i = blockIdx.x * 256 + threadIdx.x;
  int c = (i < n) ? cnt[i] : 0;
  if (i < n) dinv[i] = 1.0f / sqrtf((float)c + 1.0f);
  sh[threadIdx.x] = c;
  __syncthreads();
  for (int off = 128; off > 0; off >>= 1) {
    if (threadIdx.x < off) sh[threadIdx.x] += sh[threadIdx.x + off];
    __syncthreads();
  }
  if (threadIdx.x == 0) bsum[blockIdx.x] = sh[0];
}

__global__ __launch_bounds__(256) void scan2_kernel(const int* __restrict__ bsum,
                                                    int* __restrict__ boff,
                                                    int* __restrict__ rowptr) {
  __shared__ int sh[256];
  int t = threadIdx.x;
  int v = (t < NB_SCAN) ? bsum[t] : 0;
  sh[t] = v;
  __syncthreads();
  for (int off = 1; off < 256; off <<= 1) {
    int u = (t >= off) ? sh[t - off] : 0;
    __syncthreads();
    sh[t] += u;
    __syncthreads();
  }
  if (t < NB_SCAN) boff[t] = (t == 0) ? 0 : sh[t - 1];
  if (t == 255) rowptr[N_NODES] = sh[255];
}

__global__ __launch_bounds__(256) void scan3_kernel(const int* __restrict__ cnt,
                                                    const int* __restrict__ boff,
                                                    int* __restrict__ rowptr, int n) {
  __shared__ int sh[256];
  int i = blockIdx.x * 256 + threadIdx.x;
  int c = (i < n) ? cnt[i] : 0;
  sh[threadIdx.x] = c;
  __syncthreads();
  for (int off = 1; off < 256; off <<= 1) {
    int u = (threadIdx.x >= off) ? sh[threadIdx.x - off] : 0;
    __syncthreads();
    sh[threadIdx.x] += u;
    __syncthreads();
  }
  if (i < n) rowptr[i] = boff[blockIdx.x] + sh[threadIdx.x] - c;
}

__global__ void place_kernel(const int* __restrict__ dst, const int* __restrict__ rowptr,
                             int* __restrict__ cursor, int* __restrict__ csr, int e) {
  int i = blockIdx.x * blockDim.x + threadIdx.x;
  if (i < e) {
    int d = dst[i];
    int slot = rowptr[d] + atomicAdd(&cursor[d], 1);
    csr[slot] = i;
  }
}

// one wave per row: bitonic sort of edge ids (canonical), rewrite as (src, dinv[src])
__global__ __launch_bounds__(256) void sortrow_kernel(
    int* __restrict__ csr, float* __restrict__ csr_w, const int* __restrict__ rowptr,
    const int* __restrict__ src, const float* __restrict__ dinv, int n) {
  int wid = (blockIdx.x * 256 + threadIdx.x) >> 6;
  int lane = threadIdx.x & 63;
  if (wid >= n) return;
  int beg = rowptr[wid], len = rowptr[wid + 1] - beg;
  if (len <= 64) {
    int v = (lane < len) ? csr[beg + lane] : 0x7fffffff;
    #pragma unroll
    for (int k = 2; k <= 64; k <<= 1) {
      #pragma unroll
      for (int j = k >> 1; j >= 1; j >>= 1) {
        int other = __shfl_xor(v, j);
        int mn = min(v, other), mx = max(v, other);
        bool up = (lane & k) == 0;
        v = (((lane & j) == 0) == up) ? mn : mx;
      }
    }
    if (lane < len) {
      int s = src[v];
      csr[beg + lane] = s;
      csr_w[beg + lane] = dinv[s];
    }
  } else if (lane == 0) {   // unreachable (Poisson(16)); scratch-free fallback
    for (int a = 0; a < len; ++a)
      for (int b = a + 1; b < len; ++b) {
        int xa = csr[beg + a], xb = csr[beg + b];
        if (xb < xa) { csr[beg + a] = xb; csr[beg + b] = xa; }
      }
    for (int a = 0; a < len; ++a) {
      int s = src[csr[beg + a]];
      csr[beg + a] = s;
      csr_w[beg + a] = dinv[s];
    }
  }
}

// ---------------- conversions (x + all weights, one launch) ----------------

__global__ void cvt_all_kernel(const float* __restrict__ x, _Float16* __restrict__ xh,
                               const float* __restrict__ W0, _Float16* __restrict__ W0t,
                               const float* __restrict__ W1, _Float16* __restrict__ W1t,
                               const float* __restrict__ W2, _Float16* __restrict__ W2at) {
  constexpr int X4 = N_NODES * FEAT / 4;
  int idx = blockIdx.x * blockDim.x + threadIdx.x;
  if (idx < X4) {
    floatx4 v = ((const floatx4*)x)[idx];
    half4_t h;
    h[0] = (_Float16)v[0]; h[1] = (_Float16)v[1];
    h[2] = (_Float16)v[2]; h[3] = (_Float16)v[3];
    ((half4_t*)xh)[idx] = h;
    return;
  }
  idx -= X4;
  if (idx < FEAT * 256) {
    int c = idx / FEAT, k = idx - c * FEAT;
    W0t[idx] = (_Float16)W0[k * 256 + c];
    return;
  }
  idx -= FEAT * 256;
  if (idx < HID * 256) {
    int c = idx / HID, k = idx - c * HID;
    W1t[idx] = (_Float16)W1[k * 256 + c];
    return;
  }
  idx -= HID * 256;
  if (idx < HID * 256) {
    int c = idx / HID, k = idx - c * HID;
    W2at[idx] = (_Float16)W2[k * 256 + c];
  }
}

// ---------------- aggregation (f16 in/out, f32 accumulate, 4-edge unroll) ------
template <int F, bool BIAS, bool RELU>
__global__ __launch_bounds__(256) void agg16_kernel(
    const _Float16* __restrict__ T, const int* __restrict__ rowptr,
    const int* __restrict__ csr, const float* __restrict__ csr_w,
    const float* __restrict__ dinv, const float* __restrict__ bias,
    _Float16* __restrict__ out, int n) {
  constexpr int LPR = F / 8;
  constexpr int RPB = 256 / LPR;
  int li = threadIdx.x & (LPR - 1);
  int d = blockIdx.x * RPB + threadIdx.x / LPR;
  if (d >= n) return;
  const half8_t* Tv = (const half8_t*)T;
  int beg = rowptr[d], end = rowptr[d + 1];
  float acc[8];
  #pragma unroll
  for (int e = 0; e < 8; ++e) acc[e] = 0.f;
  int j = beg;
  for (; j + 4 <= end; j += 4) {
    int s0 = csr[j], s1 = csr[j + 1], s2 = csr[j + 2], s3 = csr[j + 3];
    float w0 = csr_w[j], w1 = csr_w[j + 1], w2 = csr_w[j + 2], w3 = csr_w[j + 3];
    half8_t v0 = Tv[(size_t)s0 * LPR + li];
    half8_t v1 = Tv[(size_t)s1 * LPR + li];
    half8_t v2 = Tv[(size_t)s2 * LPR + li];
    half8_t v3 = Tv[(size_t)s3 * LPR + li];
    #pragma unroll
    for (int e = 0; e < 8; ++e)
      acc[e] += w0 * (float)v0[e] + w1 * (float)v1[e] + w2 * (float)v2[e] + w3 * (float)v3[e];
  }
  for (; j < end; ++j) {
    int s0 = csr[j];
    float w0 = csr_w[j];
    half8_t v0 = Tv[(size_t)s0 * LPR + li];
    #pragma unroll
    for (int e = 0; e < 8; ++e) acc[e] += w0 * (float)v0[e];
  }
  float di = dinv[d];
  half8_t vs = Tv[(size_t)d * LPR + li];
  half8_t o;
  #pragma unroll
  for (int e = 0; e < 8; ++e) {
    float v = acc[e] * di + (float)vs[e] * di * di;
    if (BIAS) v += bias[li * 8 + e];
    if (RELU) v = fmaxf(v, 0.f);
    o[e] = (_Float16)v;
  }
  ((half8_t*)out)[(size_t)d * LPR + li] = o;
}

// ---- agg + bias + relu + dot(W3): t3[d] = relu(agg(T)[d] + b2) . W3
__global__ __launch_bounds__(256) void agg_dot_kernel(
    const _Float16* __restrict__ T, const int* __restrict__ rowptr,
    const int* __restrict__ csr, const float* __restrict__ csr_w,
    const float* __restrict__ dinv, const float* __restrict__ bias,
    const float* __restrict__ W3, float* __restrict__ t3, int n) {
  constexpr int LPR = 32;
  int li = threadIdx.x & (LPR - 1);
  int d = blockIdx.x * 8 + threadIdx.x / LPR;
  if (d >= n) return;
  const half8_t* Tv = (const half8_t*)T;
  int beg = rowptr[d], end = rowptr[d + 1];
  float acc[8];
  #pragma unroll
  for (int e = 0; e < 8; ++e) acc[e] = 0.f;
  int j = beg;
  for (; j + 4 <= end; j += 4) {
    int s0 = csr[j], s1 = csr[j + 1], s2 = csr[j + 2], s3 = csr[j + 3];
    float w0 = csr_w[j], w1 = csr_w[j + 1], w2 = csr_w[j + 2], w3 = csr_w[j + 3];
    half8_t v0 = Tv[(size_t)s0 * LPR + li];
    half8_t v1 = Tv[(size_t)s1 * LPR + li];
    half8_t v2 = Tv[(size_t)s2 * LPR + li];
    half8_t v3 = Tv[(size_t)s3 * LPR + li];
    #pragma unroll
    for (int e = 0; e < 8; ++e)
      acc[e] += w0 * (float)v0[e] + w1 * (float)v1[e] + w2 * (float)v2[e] + w3 * (float)v3[e];
  }
  for (; j < end; ++j) {
    int s0 = csr[j];
    float w0 = csr_w[j];
    half8_t v0 = Tv[(size_t)s0 * LPR + li];
    #pragma unroll
    for (int e = 0; e < 8; ++e) acc[e] += w0 * (float)v0[e];
  }
  float di = dinv[d];
  half8_t vs = Tv[(size_t)d * LPR + li];
  floatx4 w3a = *(const floatx4*)(W3 + li * 8);
  floatx4 w3b = *(const floatx4*)(W3 + li * 8 + 4);
  float s = 0.f;
  #pragma unroll
  for (int e = 0; e < 8; ++e) {
    float v = acc[e] * di + (float)vs[e] * di * di + bias[li * 8 + e];
    v = fmaxf(v, 0.f);
    s += v * ((e < 4) ? w3a[e] : w3b[e - 4]);
  }
  #pragma unroll
  for (int off = 1; off < 32; off <<= 1) s += __shfl_xor(s, off);
  if (li == 0) t3[d] = s;
}

// ---------------- tiled MFMA GEMM (optional fused graph-max-pool) ----------------
template <int K, bool BIAS, bool RELU, bool GIADD, bool POOL>
__global__ __launch_bounds__(256) void gemm_tile(
    const _Float16* __restrict__ A, const _Float16* __restrict__ Bt,
    const float* __restrict__ bias, const float* __restrict__ gi2,
    const int* __restrict__ batch, _Float16* __restrict__ C,
    int* __restrict__ poolI, int nrows) {
  constexpr int ROWB = K * 2;
  constexpr int CPR = K / 8;
  __shared__ _Float16 smem[128 * K];
  __shared__ int Pred[2][HID];
  char* sb = (char*)smem;
  int tid = threadIdx.x;
  int row0 = blockIdx.x * 128;
  if (POOL) { Pred[0][tid] = 0; Pred[1][tid] = 0; }

  #pragma unroll
  for (int it = 0; it < K / 16; ++it) {
    int e = it * 256 + tid;
    int r = e / CPR;
    int cof = (e - r * CPR) * 16;
    int grow = min(row0 + r, nrows - 1);
    half8_t v = *(const half8_t*)(A + (size_t)grow * K + cof / 2);
    *(half8_t*)&sb[r * ROWB + (cof ^ ((r & 7) << 4))] = v;
  }
  __syncthreads();

  int lane = tid & 63, wv = tid >> 6;
  int rlo = lane & 15, khi = lane >> 4;
  int cw0 = wv * 64;
  floatx4 acc[8][4];
  #pragma unroll
  for (int h = 0; h < 8; ++h)
    #pragma unroll
    for (int g = 0; g < 4; ++g)
      { acc[h][g][0] = 0.f; acc[h][g][1] = 0.f; acc[h][g][2] = 0.f; acc[h][g][3] = 0.f; }

  for (int kc = 0; kc < K; kc += 32) {
    int kbyte = kc * 2 + khi * 16;
    half8_t xa[8];
    #pragma unroll
    for (int h = 0; h < 8; ++h) {
      int r = h * 16 + rlo;
      xa[h] = *(half8_t*)&sb[r * ROWB + (kbyte ^ ((r & 7) << 4))];
    }
    #pragma unroll
    for (int g = 0; g < 4; ++g) {
      half8_t wb = *(const half8_t*)(Bt + (size_t)(cw0 + g * 16 + rlo) * K + kc + khi * 8);
      #pragma unroll
      for (int h = 0; h < 8; ++h)
        acc[h][g] = __builtin_amdgcn_mfma_f32_16x16x32_f16(wb, xa[h], acc[h][g], 0, 0, 0);
    }
  }

  int g0 = 0;
  if (POOL) g0 = batch[min(row0, nrows - 1)];
  bool rvalid[8]; int rwh[8];
  #pragma unroll
  for (int h = 0; h < 8; ++h) {
    int crow = row0 + h * 16 + rlo;
    rvalid[h] = crow < nrows;
    rwh[h] = (POOL && rvalid[h]) ? (batch[crow] != g0) : 0;
  }

  #pragma unroll
  for (int g = 0; g < 4; ++g) {
    int c0 = cw0 + g * 16 + khi * 4;
    floatx4 pm0 = {0.f, 0.f, 0.f, 0.f}, pm1 = {0.f, 0.f, 0.f, 0.f};
    #pragma unroll
    for (int h = 0; h < 8; ++h) {
      if (!rvalid[h]) continue;
      int crow = row0 + h * 16 + rlo;
      floatx4 v = acc[h][g];
      if (BIAS) v += *(const floatx4*)(bias + c0);
      if (GIADD) v += *(const floatx4*)(gi2 + (size_t)batch[crow] * HID + c0);
      if (RELU) {
        v[0] = fmaxf(v[0], 0.f); v[1] = fmaxf(v[1], 0.f);
        v[2] = fmaxf(v[2], 0.f); v[3] = fmaxf(v[3], 0.f);
      }
      if (POOL) {
        if (rwh[h]) { pm1[0] = fmaxf(pm1[0], v[0]); pm1[1] = fmaxf(pm1[1], v[1]);
                      pm1[2] = fmaxf(pm1[2], v[2]); pm1[3] = fmaxf(pm1[3], v[3]); }
        else        { pm0[0] = fmaxf(pm0[0], v[0]); pm0[1] = fmaxf(pm0[1], v[1]);
                      pm0[2] = fmaxf(pm0[2], v[2]); pm0[3] = fmaxf(pm0[3], v[3]); }
      }
      half4_t hv;
      hv[0] = (_Float16)v[0]; hv[1] = (_Float16)v[1];
      hv[2] = (_Float16)v[2]; hv[3] = (_Float16)v[3];
      *(half4_t*)(C + (size_t)crow * HID + c0) = hv;
    }
    if (POOL) {
      #pragma unroll
      for (int e = 0; e < 4; ++e) {
        if (pm0[e] > 0.f) atomicMax(&Pred[0][c0 + e], __float_as_int(pm0[e]));
        if (pm1[e] > 0.f) atomicMax(&Pred[1][c0 + e], __float_as_int(pm1[e]));
      }
    }
  }

  if (POOL) {
    __syncthreads();
    int glast = batch[min(row0 + 127, nrows - 1)];
    atomicMax(&poolI[g0 * HID + tid], Pred[0][tid]);
    if (glast != g0) atomicMax(&poolI[glast * HID + tid], Pred[1][tid]);
  }
}

// ---------------- pooled -> fc1 -> @W2[256:512] ----------------
__global__ __launch_bounds__(256) void pool2_kernel(const int* __restrict__ poolI,
                                                    const float* __restrict__ Wf,
                                                    const float* __restrict__ bf,
                                                    const float* __restrict__ W2,
                                                    float* __restrict__ gi2) {
  __shared__ float P[HID];
  __shared__ float GI[HID];
  int g = blockIdx.x;
  int c = threadIdx.x;
  P[c] = __int_as_float(poolI[g * HID + c]);
  __syncthreads();
  float a = 0.f;
  for (int k = 0; k < HID; ++k) a += P[k] * Wf[k * HID + c];
  GI[c] = a + bf[c];
  __syncthreads();
  float a2 = 0.f;
  for (int k = 0; k < HID; ++k) a2 += GI[k] * W2[(HID + k) * HID + c];
  gi2[g * HID + c] = a2;
}

__global__ void final_kernel(const float* __restrict__ t3, const int* __restrict__ rowptr,
                             const int* __restrict__ csr, const float* __restrict__ csr_w,
                             const float* __restrict__ dinv, const float* __restrict__ b3,
                             float* __restrict__ out, int n) {
  int d = blockIdx.x * blockDim.x + threadIdx.x;
  if (d >= n) return;
  float acc = 0.f;
  int beg = rowptr[d], end = rowptr[d + 1];
  for (int j = beg; j < end; ++j) acc += csr_w[j] * t3[csr[j]];
  float di = dinv[d];
  out[d] = acc * di + t3[d] * di * di + b3[0];
}

// ---------------- launcher ----------------

extern "C" void kernel_launch(void* const* d_in, const int* in_sizes, int n_in,
                              void* d_out, int out_size, void* d_ws, size_t ws_size,
                              hipStream_t stream) {
  const float* x   = (const float*)d_in[0];
  const int* src   = (const int*)d_in[1];
  const int* dst   = (const int*)d_in[2];
  const int* batch = (const int*)d_in[3];
  const float* W0 = (const float*)d_in[4];
  const float* b0 = (const float*)d_in[5];
  const float* Wf = (const float*)d_in[6];
  const float* bf = (const float*)d_in[7];
  const float* W1 = (const float*)d_in[8];
  const float* b1 = (const float*)d_in[9];
  const float* W2 = (const float*)d_in[10];
  const float* b2 = (const float*)d_in[11];
  const float* W3 = (const float*)d_in[12];
  const float* b3 = (const float*)d_in[13];
  float* out = (float*)d_out;

  char* p = (char*)d_ws;
  auto alloc = [&](size_t bytes) { char* q = p; p += (bytes + 255) & ~(size_t)255; return q; };
  _Float16* hA   = (_Float16*)alloc((size_t)N_NODES * HID * 2);
  _Float16* hB   = (_Float16*)alloc((size_t)N_NODES * HID * 2);
  _Float16* xh   = (_Float16*)alloc((size_t)N_NODES * FEAT * 2);
  _Float16* W0t  = (_Float16*)alloc((size_t)HID * FEAT * 2);
  _Float16* W1t  = (_Float16*)alloc((size_t)HID * HID * 2);
  _Float16* W2at = (_Float16*)alloc((size_t)HID * HID * 2);
  int*   cnt    = (int*)alloc((size_t)N_NODES * 4);
  int*   rowptr = (int*)alloc((size_t)(N_NODES + 1) * 4);
  int*   cursor = (int*)alloc((size_t)N_NODES * 4);
  int*   csr    = (int*)alloc((size_t)N_EDGES * 4);
  float* csrw   = (float*)alloc((size_t)N_EDGES * 4);
  float* dinv   = (float*)alloc((size_t)N_NODES * 4);
  int*   bsum   = (int*)alloc(NB_SCAN * 4);
  int*   boff   = (int*)alloc(NB_SCAN * 4);
  int*   poolI  = (int*)alloc((size_t)N_GRAPHS * HID * 4);
  float* gi2    = (float*)alloc((size_t)N_GRAPHS * HID * 4);
  float* t3     = (float*)alloc((size_t)N_NODES * 4);

  hipMemsetAsync(cnt, 0, (size_t)N_NODES * 4, stream);
  hipMemsetAsync(cursor, 0, (size_t)N_NODES * 4, stream);
  hipMemsetAsync(poolI, 0, (size_t)N_GRAPHS * HID * 4, stream);

  int eb = (N_EDGES + 255) / 256;
  int nb = NB_SCAN;

  constexpr int CVT_TOT = N_NODES * FEAT / 4 + (FEAT + 2 * HID) * 256;
  cvt_all_kernel<<<(CVT_TOT + 255) / 256, 256, 0, stream>>>(x, xh, W0, W0t, W1, W1t, W2, W2at);

  hist_kernel<<<eb, 256, 0, stream>>>(dst, cnt, N_EDGES);
  scan1_kernel<<<nb, 256, 0, stream>>>(cnt, dinv, bsum, N_NODES);
  scan2_kernel<<<1, 256, 0, stream>>>(bsum, boff, rowptr);
  scan3_kernel<<<nb, 256, 0, stream>>>(cnt, boff, rowptr, N_NODES);
  place_kernel<<<eb, 256, 0, stream>>>(dst, rowptr, cursor, csr, N_EDGES);
  sortrow_kernel<<<(N_NODES * 64 + 255) / 256, 256, 0, stream>>>(csr, csrw, rowptr, src, dinv, N_NODES);

  int gb = (N_NODES + 127) / 128;

  // conv0 (+fused max-pool into poolI)
  agg16_kernel<FEAT, false, false><<<(N_NODES + 15) / 16, 256, 0, stream>>>(xh, rowptr, csr, csrw, dinv, nullptr, hA, N_NODES);
  gemm_tile<FEAT, true, true, false, true><<<gb, 256, 0, stream>>>(hA, W0t, b0, nullptr, batch, hB, poolI, N_NODES);

  // gi2 = (pooled @ Wf + bf) @ W2[256:512]
  pool2_kernel<<<N_GRAPHS, 256, 0, stream>>>(poolI, Wf, bf, W2, gi2);

  // conv1 #1
  agg16_kernel<HID, false, false><<<(N_NODES + 7) / 8, 256, 0, stream>>>(hB, rowptr, csr, csrw, dinv, nullptr, hA, N_NODES);
  gemm_tile<HID, true, true, false, false><<<gb, 256, 0, stream>>>(hA, W1t, b1, nullptr, nullptr, hB, nullptr, N_NODES);

  // conv1 #2
  agg16_kernel<HID, false, false><<<(N_NODES + 7) / 8, 256, 0, stream>>>(hB, rowptr, csr, csrw, dinv, nullptr, hA, N_NODES);
  gemm_tile<HID, true, true, false, false><<<gb, 256, 0, stream>>>(hA, W1t, b1, nullptr, nullptr, hB, nullptr, N_NODES);

  // conv2: T2 = loc2@W2a + gi2[batch] -> hA ; then agg+bias+relu+dot(W3) -> t3
  gemm_tile<HID, false, false, true, false><<<gb, 256, 0, stream>>>(hB, W2at, nullptr, gi2, batch, hA, nullptr, N_NODES);
  agg_dot_kernel<<<(N_NODES + 7) / 8, 256, 0, stream>>>(hA, rowptr, csr, csrw, dinv, b2, W3, t3, N_NODES);

  // conv3 aggregation (scalar)
  final_kernel<<<(N_NODES + 255) / 256, 256, 0, stream>>>(t3, rowptr, csr, csrw, dinv, b3, out, N_NODES);
}

// Round 9
// 420.588 us; speedup vs baseline: 1.9117x; 1.1527x over previous
//
#include <hip/hip_runtime.h>

#define N_NODES 50000
#define N_EDGES 800000
#define FEAT 128
#define HID 256
#define N_GRAPHS 64
#define NB_SCAN ((N_NODES + 255) / 256)

typedef float floatx4 __attribute__((ext_vector_type(4)));
typedef _Float16 half4_t __attribute__((ext_vector_type(4)));
typedef _Float16 half8_t __attribute__((ext_vector_type(8)));

// ---------------- graph preprocessing ----------------

__global__ void hist_kernel(const int* __restrict__ dst, int* __restrict__ cnt, int e) {
  int i = blockIdx.x * blockDim.x + threadIdx.x;
  if (i < e) atomicAdd(&cnt[dst[i]], 1);
}

__global__ __launch_bounds__(256) void scan1_kernel(const int* __restrict__ cnt,
                                                    float* __restrict__ dinv,
                                                    int* __restrict__ bsum, int n) {
  __shared__ int sh[256];
  int i = blockIdx.x * 256 + threadIdx.x;
  int c = (i < n) ? cnt[i] : 0;
  if (i < n) dinv[i] = 1.0f / sqrtf((float)c + 1.0f);
  sh[threadIdx.x] = c;
  __syncthreads();
  for (int off = 128; off > 0; off >>= 1) {
    if (threadIdx.x < off) sh[threadIdx.x] += sh[threadIdx.x + off];
    __syncthreads();
  }
  if (threadIdx.x == 0) bsum[blockIdx.x] = sh[0];
}

__global__ __launch_bounds__(256) void scan2_kernel(const int* __restrict__ bsum,
                                                    int* __restrict__ boff,
                                                    int* __restrict__ rowptr) {
  __shared__ int sh[256];
  int t = threadIdx.x;
  int v = (t < NB_SCAN) ? bsum[t] : 0;
  sh[t] = v;
  __syncthreads();
  for (int off = 1; off < 256; off <<= 1) {
    int u = (t >= off) ? sh[t - off] : 0;
    __syncthreads();
    sh[t] += u;
    __syncthreads();
  }
  if (t < NB_SCAN) boff[t] = (t == 0) ? 0 : sh[t - 1];
  if (t == 255) rowptr[N_NODES] = sh[255];
}

__global__ __launch_bounds__(256) void scan3_kernel(const int* __restrict__ cnt,
                                                    const int* __restrict__ boff,
                                                    int* __restrict__ rowptr, int n) {
  __shared__ int sh[256];
  int i = blockIdx.x * 256 + threadIdx.x;
  int c = (i < n) ? cnt[i] : 0;
  sh[threadIdx.x] = c;
  __syncthreads();
  for (int off = 1; off < 256; off <<= 1) {
    int u = (threadIdx.x >= off) ? sh[threadIdx.x - off] : 0;
    __syncthreads();
    sh[threadIdx.x] += u;
    __syncthreads();
  }
  if (i < n) rowptr[i] = boff[blockIdx.x] + sh[threadIdx.x] - c;
}

__global__ void place_kernel(const int* __restrict__ dst, const int* __restrict__ rowptr,
                             int* __restrict__ cursor, int* __restrict__ csr, int e) {
  int i = blockIdx.x * blockDim.x + threadIdx.x;
  if (i < e) {
    int d = dst[i];
    int slot = rowptr[d] + atomicAdd(&cursor[d], 1);
    csr[slot] = i;
  }
}

// one wave per row: bitonic sort of edge ids (canonical), rewrite as (src, dinv[src])
__global__ __launch_bounds__(256) void sortrow_kernel(
    int* __restrict__ csr, float* __restrict__ csr_w, const int* __restrict__ rowptr,
    const int* __restrict__ src, const float* __restrict__ dinv, int n) {
  int wid = (blockIdx.x * 256 + threadIdx.x) >> 6;
  int lane = threadIdx.x & 63;
  if (wid >= n) return;
  int beg = rowptr[wid], len = rowptr[wid + 1] - beg;
  if (len <= 64) {
    int v = (lane < len) ? csr[beg + lane] : 0x7fffffff;
    #pragma unroll
    for (int k = 2; k <= 64; k <<= 1) {
      #pragma unroll
      for (int j = k >> 1; j >= 1; j >>= 1) {
        int other = __shfl_xor(v, j);
        int mn = min(v, other), mx = max(v, other);
        bool up = (lane & k) == 0;
        v = (((lane & j) == 0) == up) ? mn : mx;
      }
    }
    if (lane < len) {
      int s = src[v];
      csr[beg + lane] = s;
      csr_w[beg + lane] = dinv[s];
    }
  } else if (lane == 0) {   // unreachable (Poisson(16)); scratch-free fallback
    for (int a = 0; a < len; ++a)
      for (int b = a + 1; b < len; ++b) {
        int xa = csr[beg + a], xb = csr[beg + b];
        if (xb < xa) { csr[beg + a] = xb; csr[beg + b] = xa; }
      }
    for (int a = 0; a < len; ++a) {
      int s = src[csr[beg + a]];
      csr[beg + a] = s;
      csr_w[beg + a] = dinv[s];
    }
  }
}

// ---------------- conversions (x + all weights, one launch) ----------------

__global__ void cvt_all_kernel(const float* __restrict__ x, _Float16* __restrict__ xh,
                               const float* __restrict__ W0, _Float16* __restrict__ W0t,
                               const float* __restrict__ W1, _Float16* __restrict__ W1t,
                               const float* __restrict__ W2, _Float16* __restrict__ W2at) {
  constexpr int X4 = N_NODES * FEAT / 4;
  int idx = blockIdx.x * blockDim.x + threadIdx.x;
  if (idx < X4) {
    floatx4 v = ((const floatx4*)x)[idx];
    half4_t h;
    h[0] = (_Float16)v[0]; h[1] = (_Float16)v[1];
    h[2] = (_Float16)v[2]; h[3] = (_Float16)v[3];
    ((half4_t*)xh)[idx] = h;
    return;
  }
  idx -= X4;
  if (idx < FEAT * 256) {
    int c = idx / FEAT, k = idx - c * FEAT;
    W0t[idx] = (_Float16)W0[k * 256 + c];
    return;
  }
  idx -= FEAT * 256;
  if (idx < HID * 256) {
    int c = idx / HID, k = idx - c * HID;
    W1t[idx] = (_Float16)W1[k * 256 + c];
    return;
  }
  idx -= HID * 256;
  if (idx < HID * 256) {
    int c = idx / HID, k = idx - c * HID;
    W2at[idx] = (_Float16)W2[k * 256 + c];
  }
}

// ---------------- fused agg -> (LDS tile) -> MFMA GEMM [-> chained GEMM2] -------
// Block = 512 threads (8 waves) owns 128 output rows.
// Agg phase: aggfull(T) (edge sum * di + self * di^2) -> f16 swizzled LDS tile.
// GEMM1: C1 = relu(tile @ Bt^T + bias). POOL: per-graph max of C1 -> poolI.
// CHAIN: C1 stays in LDS, C = C1 @ Bt2^T + gi2[batch]; else C = C1.
template <int K, bool POOL, bool CHAIN>
__global__ __launch_bounds__(512, 4) void fused_kernel(
    const _Float16* __restrict__ T, const int* __restrict__ rowptr,
    const int* __restrict__ csr, const float* __restrict__ csr_w,
    const float* __restrict__ dinv,
    const _Float16* __restrict__ Bt, const float* __restrict__ bias,
    const _Float16* __restrict__ Bt2, const float* __restrict__ gi2,
    const int* __restrict__ batch, int* __restrict__ poolI,
    _Float16* __restrict__ C, int nrows) {
  constexpr int ROWB = K * 2;
  __shared__ _Float16 smem[128 * K];
  __shared__ int Pred[2][HID];
  char* sb = (char*)smem;
  int tid = threadIdx.x;
  int row0 = blockIdx.x * 128;
  if (POOL && tid < 256) { Pred[0][tid] = 0; Pred[1][tid] = 0; }

  // ---- agg phase ----
  {
    constexpr int LPR = K / 8;          // lanes per row
    constexpr int RPP = 512 / LPR;      // rows per pass
    int li = tid & (LPR - 1);
    int rl = tid / LPR;
    const half8_t* Tv = (const half8_t*)T;
    #pragma unroll
    for (int pass = 0; pass < 128 / RPP; ++pass) {
      int r = pass * RPP + rl;
      int d = row0 + r;
      half8_t o;
      if (d < nrows) {
        int beg = rowptr[d], end = rowptr[d + 1];
        float acc[8];
        #pragma unroll
        for (int e = 0; e < 8; ++e) acc[e] = 0.f;
        int j = beg;
        for (; j + 4 <= end; j += 4) {
          int s0 = csr[j], s1 = csr[j + 1], s2 = csr[j + 2], s3 = csr[j + 3];
          float w0 = csr_w[j], w1 = csr_w[j + 1], w2 = csr_w[j + 2], w3 = csr_w[j + 3];
          half8_t v0 = Tv[(size_t)s0 * LPR + li];
          half8_t v1 = Tv[(size_t)s1 * LPR + li];
          half8_t v2 = Tv[(size_t)s2 * LPR + li];
          half8_t v3 = Tv[(size_t)s3 * LPR + li];
          #pragma unroll
          for (int e = 0; e < 8; ++e)
            acc[e] += w0 * (float)v0[e] + w1 * (float)v1[e] + w2 * (float)v2[e] + w3 * (float)v3[e];
        }
        for (; j < end; ++j) {
          int s0 = csr[j];
          float w0 = csr_w[j];
          half8_t v0 = Tv[(size_t)s0 * LPR + li];
          #pragma unroll
          for (int e = 0; e < 8; ++e) acc[e] += w0 * (float)v0[e];
        }
        float di = dinv[d];
        half8_t vs = Tv[(size_t)d * LPR + li];
        #pragma unroll
        for (int e = 0; e < 8; ++e)
          o[e] = (_Float16)(acc[e] * di + (float)vs[e] * di * di);
      } else {
        #pragma unroll
        for (int e = 0; e < 8; ++e) o[e] = (_Float16)0.f;
      }
      *(half8_t*)&sb[r * ROWB + ((li * 16) ^ ((r & 7) << 4))] = o;
    }
  }
  __syncthreads();

  // ---- GEMM1: 8 waves, wave owns 32 cols x 128 rows ----
  int lane = tid & 63, wv = tid >> 6;
  int rlo = lane & 15, khi = lane >> 4;
  int cw0 = wv * 32;
  floatx4 acc[8][2];
  #pragma unroll
  for (int h = 0; h < 8; ++h)
    #pragma unroll
    for (int g = 0; g < 2; ++g)
      { acc[h][g][0] = 0.f; acc[h][g][1] = 0.f; acc[h][g][2] = 0.f; acc[h][g][3] = 0.f; }

  for (int kc = 0; kc < K; kc += 32) {
    int kbyte = kc * 2 + khi * 16;
    half8_t xa[8];
    #pragma unroll
    for (int h = 0; h < 8; ++h) {
      int r = h * 16 + rlo;
      xa[h] = *(half8_t*)&sb[r * ROWB + (kbyte ^ ((r & 7) << 4))];
    }
    #pragma unroll
    for (int g = 0; g < 2; ++g) {
      half8_t wb = *(const half8_t*)(Bt + (size_t)(cw0 + g * 16 + rlo) * K + kc + khi * 8);
      #pragma unroll
      for (int h = 0; h < 8; ++h)
        acc[h][g] = __builtin_amdgcn_mfma_f32_16x16x32_f16(wb, xa[h], acc[h][g], 0, 0, 0);
    }
  }

  // GEMM1 epilogue: bias + relu
  #pragma unroll
  for (int g = 0; g < 2; ++g) {
    int c0 = cw0 + g * 16 + khi * 4;
    floatx4 bv = *(const floatx4*)(bias + c0);
    #pragma unroll
    for (int h = 0; h < 8; ++h) {
      floatx4 v = acc[h][g] + bv;
      v[0] = fmaxf(v[0], 0.f); v[1] = fmaxf(v[1], 0.f);
      v[2] = fmaxf(v[2], 0.f); v[3] = fmaxf(v[3], 0.f);
      acc[h][g] = v;
    }
  }

  if (POOL) {
    int g0 = batch[min(row0, nrows - 1)];
    #pragma unroll
    for (int g = 0; g < 2; ++g) {
      int c0 = cw0 + g * 16 + khi * 4;
      floatx4 pm0 = {0.f, 0.f, 0.f, 0.f}, pm1 = {0.f, 0.f, 0.f, 0.f};
      #pragma unroll
      for (int h = 0; h < 8; ++h) {
        int crow = row0 + h * 16 + rlo;
        if (crow >= nrows) continue;
        floatx4 v = acc[h][g];
        if (batch[crow] != g0) {
          pm1[0] = fmaxf(pm1[0], v[0]); pm1[1] = fmaxf(pm1[1], v[1]);
          pm1[2] = fmaxf(pm1[2], v[2]); pm1[3] = fmaxf(pm1[3], v[3]);
        } else {
          pm0[0] = fmaxf(pm0[0], v[0]); pm0[1] = fmaxf(pm0[1], v[1]);
          pm0[2] = fmaxf(pm0[2], v[2]); pm0[3] = fmaxf(pm0[3], v[3]);
        }
      }
      #pragma unroll
      for (int e = 0; e < 4; ++e) {
        if (pm0[e] > 0.f) atomicMax(&Pred[0][c0 + e], __float_as_int(pm0[e]));
        if (pm1[e] > 0.f) atomicMax(&Pred[1][c0 + e], __float_as_int(pm1[e]));
      }
    }
  }

  if (!CHAIN) {
    #pragma unroll
    for (int h = 0; h < 8; ++h) {
      int crow = row0 + h * 16 + rlo;
      if (crow >= nrows) continue;
      #pragma unroll
      for (int g = 0; g < 2; ++g) {
        int c0 = cw0 + g * 16 + khi * 4;
        floatx4 v = acc[h][g];
        half4_t hv;
        hv[0] = (_Float16)v[0]; hv[1] = (_Float16)v[1];
        hv[2] = (_Float16)v[2]; hv[3] = (_Float16)v[3];
        *(half4_t*)(C + (size_t)crow * HID + c0) = hv;
      }
    }
  } else {
    // write C1 back into LDS (reuse A-tile buffer), then GEMM2 with Bt2 + gi2
    __syncthreads();
    #pragma unroll
    for (int h = 0; h < 8; ++h) {
      int r = h * 16 + rlo;
      #pragma unroll
      for (int g = 0; g < 2; ++g) {
        int c0 = cw0 + g * 16 + khi * 4;
        floatx4 v = acc[h][g];
        half4_t hv;
        hv[0] = (_Float16)v[0]; hv[1] = (_Float16)v[1];
        hv[2] = (_Float16)v[2]; hv[3] = (_Float16)v[3];
        *(half4_t*)&sb[r * ROWB + ((c0 * 2) ^ ((r & 7) << 4))] = hv;
      }
    }
    __syncthreads();
    floatx4 acc2[8][2];
    #pragma unroll
    for (int h = 0; h < 8; ++h)
      #pragma unroll
      for (int g = 0; g < 2; ++g)
        { acc2[h][g][0] = 0.f; acc2[h][g][1] = 0.f; acc2[h][g][2] = 0.f; acc2[h][g][3] = 0.f; }
    for (int kc = 0; kc < K; kc += 32) {
      int kbyte = kc * 2 + khi * 16;
      half8_t xa[8];
      #pragma unroll
      for (int h = 0; h < 8; ++h) {
        int r = h * 16 + rlo;
        xa[h] = *(half8_t*)&sb[r * ROWB + (kbyte ^ ((r & 7) << 4))];
      }
      #pragma unroll
      for (int g = 0; g < 2; ++g) {
        half8_t wb = *(const half8_t*)(Bt2 + (size_t)(cw0 + g * 16 + rlo) * K + kc + khi * 8);
        #pragma unroll
        for (int h = 0; h < 8; ++h)
          acc2[h][g] = __builtin_amdgcn_mfma_f32_16x16x32_f16(wb, xa[h], acc2[h][g], 0, 0, 0);
      }
    }
    #pragma unroll
    for (int h = 0; h < 8; ++h) {
      int crow = row0 + h * 16 + rlo;
      if (crow >= nrows) continue;
      const float* gp = gi2 + (size_t)batch[crow] * HID;
      #pragma unroll
      for (int g = 0; g < 2; ++g) {
        int c0 = cw0 + g * 16 + khi * 4;
        floatx4 v = acc2[h][g] + *(const floatx4*)(gp + c0);
        half4_t hv;
        hv[0] = (_Float16)v[0]; hv[1] = (_Float16)v[1];
        hv[2] = (_Float16)v[2]; hv[3] = (_Float16)v[3];
        *(half4_t*)(C + (size_t)crow * HID + c0) = hv;
      }
    }
  }

  if (POOL) {
    __syncthreads();
    if (tid < 256) {
      int g0 = batch[min(row0, nrows - 1)];
      int glast = batch[min(row0 + 127, nrows - 1)];
      atomicMax(&poolI[g0 * HID + tid], Pred[0][tid]);
      if (glast != g0) atomicMax(&poolI[glast * HID + tid], Pred[1][tid]);
    }
  }
}

// ---- agg + bias + relu + dot(W3): t3[d] = relu(aggfull(T)[d] + b2) . W3
__global__ __launch_bounds__(256) void agg_dot_kernel(
    const _Float16* __restrict__ T, const int* __restrict__ rowptr,
    const int* __restrict__ csr, const float* __restrict__ csr_w,
    const float* __restrict__ dinv, const float* __restrict__ bias,
    const float* __restrict__ W3, float* __restrict__ t3, int n) {
  constexpr int LPR = 32;
  int li = threadIdx.x & (LPR - 1);
  int d = blockIdx.x * 8 + threadIdx.x / LPR;
  if (d >= n) return;
  const half8_t* Tv = (const half8_t*)T;
  int beg = rowptr[d], end = rowptr[d + 1];
  float acc[8];
  #pragma unroll
  for (int e = 0; e < 8; ++e) acc[e] = 0.f;
  int j = beg;
  for (; j + 4 <= end; j += 4) {
    int s0 = csr[j], s1 = csr[j + 1], s2 = csr[j + 2], s3 = csr[j + 3];
    float w0 = csr_w[j], w1 = csr_w[j + 1], w2 = csr_w[j + 2], w3 = csr_w[j + 3];
    half8_t v0 = Tv[(size_t)s0 * LPR + li];
    half8_t v1 = Tv[(size_t)s1 * LPR + li];
    half8_t v2 = Tv[(size_t)s2 * LPR + li];
    half8_t v3 = Tv[(size_t)s3 * LPR + li];
    #pragma unroll
    for (int e = 0; e < 8; ++e)
      acc[e] += w0 * (float)v0[e] + w1 * (float)v1[e] + w2 * (float)v2[e] + w3 * (float)v3[e];
  }
  for (; j < end; ++j) {
    int s0 = csr[j];
    float w0 = csr_w[j];
    half8_t v0 = Tv[(size_t)s0 * LPR + li];
    #pragma unroll
    for (int e = 0; e < 8; ++e) acc[e] += w0 * (float)v0[e];
  }
  float di = dinv[d];
  half8_t vs = Tv[(size_t)d * LPR + li];
  floatx4 w3a = *(const floatx4*)(W3 + li * 8);
  floatx4 w3b = *(const floatx4*)(W3 + li * 8 + 4);
  float s = 0.f;
  #pragma unroll
  for (int e = 0; e < 8; ++e) {
    float v = acc[e] * di + (float)vs[e] * di * di + bias[li * 8 + e];
    v = fmaxf(v, 0.f);
    s += v * ((e < 4) ? w3a[e] : w3b[e - 4]);
  }
  #pragma unroll
  for (int off = 1; off < 32; off <<= 1) s += __shfl_xor(s, off);
  if (li == 0) t3[d] = s;
}

// ---------------- pooled -> fc1 -> @W2[256:512] ----------------
__global__ __launch_bounds__(256) void pool2_kernel(const int* __restrict__ poolI,
                                                    const float* __restrict__ Wf,
                                                    const float* __restrict__ bf,
                                                    const float* __restrict__ W2,
                                                    float* __restrict__ gi2) {
  __shared__ float P[HID];
  __shared__ float GI[HID];
  int g = blockIdx.x;
  int c = threadIdx.x;
  P[c] = __int_as_float(poolI[g * HID + c]);
  __syncthreads();
  float a = 0.f;
  for (int k = 0; k < HID; ++k) a += P[k] * Wf[k * HID + c];
  GI[c] = a + bf[c];
  __syncthreads();
  float a2 = 0.f;
  for (int k = 0; k < HID; ++k) a2 += GI[k] * W2[(HID + k) * HID + c];
  gi2[g * HID + c] = a2;
}

__global__ void final_kernel(const float* __restrict__ t3, const int* __restrict__ rowptr,
                             const int* __restrict__ csr, const float* __restrict__ csr_w,
                             const float* __restrict__ dinv, const float* __restrict__ b3,
                             float* __restrict__ out, int n) {
  int d = blockIdx.x * blockDim.x + threadIdx.x;
  if (d >= n) return;
  float acc = 0.f;
  int beg = rowptr[d], end = rowptr[d + 1];
  for (int j = beg; j < end; ++j) acc += csr_w[j] * t3[csr[j]];
  float di = dinv[d];
  out[d] = acc * di + t3[d] * di * di + b3[0];
}

// ---------------- launcher ----------------

extern "C" void kernel_launch(void* const* d_in, const int* in_sizes, int n_in,
                              void* d_out, int out_size, void* d_ws, size_t ws_size,
                              hipStream_t stream) {
  const float* x   = (const float*)d_in[0];
  const int* src   = (const int*)d_in[1];
  const int* dst   = (const int*)d_in[2];
  const int* batch = (const int*)d_in[3];
  const float* W0 = (const float*)d_in[4];
  const float* b0 = (const float*)d_in[5];
  const float* Wf = (const float*)d_in[6];
  const float* bf = (const float*)d_in[7];
  const float* W1 = (const float*)d_in[8];
  const float* b1 = (const float*)d_in[9];
  const float* W2 = (const float*)d_in[10];
  const float* b2 = (const float*)d_in[11];
  const float* W3 = (const float*)d_in[12];
  const float* b3 = (const float*)d_in[13];
  float* out = (float*)d_out;

  char* p = (char*)d_ws;
  auto alloc = [&](size_t bytes) { char* q = p; p += (bytes + 255) & ~(size_t)255; return q; };
  _Float16* hA   = (_Float16*)alloc((size_t)N_NODES * HID * 2);
  _Float16* hB   = (_Float16*)alloc((size_t)N_NODES * HID * 2);
  _Float16* xh   = (_Float16*)alloc((size_t)N_NODES * FEAT * 2);
  _Float16* W0t  = (_Float16*)alloc((size_t)HID * FEAT * 2);
  _Float16* W1t  = (_Float16*)alloc((size_t)HID * HID * 2);
  _Float16* W2at = (_Float16*)alloc((size_t)HID * HID * 2);
  int*   cnt    = (int*)alloc((size_t)N_NODES * 4);
  int*   rowptr = (int*)alloc((size_t)(N_NODES + 1) * 4);
  int*   cursor = (int*)alloc((size_t)N_NODES * 4);
  int*   csr    = (int*)alloc((size_t)N_EDGES * 4);
  float* csrw   = (float*)alloc((size_t)N_EDGES * 4);
  float* dinv   = (float*)alloc((size_t)N_NODES * 4);
  int*   bsum   = (int*)alloc(NB_SCAN * 4);
  int*   boff   = (int*)alloc(NB_SCAN * 4);
  int*   poolI  = (int*)alloc((size_t)N_GRAPHS * HID * 4);
  float* gi2    = (float*)alloc((size_t)N_GRAPHS * HID * 4);
  float* t3     = (float*)alloc((size_t)N_NODES * 4);

  hipMemsetAsync(cnt, 0, (size_t)N_NODES * 4, stream);
  hipMemsetAsync(cursor, 0, (size_t)N_NODES * 4, stream);
  hipMemsetAsync(poolI, 0, (size_t)N_GRAPHS * HID * 4, stream);

  int eb = (N_EDGES + 255) / 256;
  int nb = NB_SCAN;

  constexpr int CVT_TOT = N_NODES * FEAT / 4 + (FEAT + 2 * HID) * 256;
  cvt_all_kernel<<<(CVT_TOT + 255) / 256, 256, 0, stream>>>(x, xh, W0, W0t, W1, W1t, W2, W2at);

  hist_kernel<<<eb, 256, 0, stream>>>(dst, cnt, N_EDGES);
  scan1_kernel<<<nb, 256, 0, stream>>>(cnt, dinv, bsum, N_NODES);
  scan2_kernel<<<1, 256, 0, stream>>>(bsum, boff, rowptr);
  scan3_kernel<<<nb, 256, 0, stream>>>(cnt, boff, rowptr, N_NODES);
  place_kernel<<<eb, 256, 0, stream>>>(dst, rowptr, cursor, csr, N_EDGES);
  sortrow_kernel<<<(N_NODES * 64 + 255) / 256, 256, 0, stream>>>(csr, csrw, rowptr, src, dinv, N_NODES);

  int gb = (N_NODES + 127) / 128;

  // conv0 fused: agg(xh) -> LDS -> GEMM W0 (+b0, relu) -> hB, fused pool -> poolI
  fused_kernel<FEAT, true, false><<<gb, 512, 0, stream>>>(
      xh, rowptr, csr, csrw, dinv, W0t, b0, nullptr, nullptr, batch, poolI, hB, N_NODES);

  // gi2 = (pooled @ Wf + bf) @ W2[256:512]
  pool2_kernel<<<N_GRAPHS, 256, 0, stream>>>(poolI, Wf, bf, W2, gi2);

  // conv1 #1 fused: agg(hB) -> GEMM W1 (+b1, relu) -> hA
  fused_kernel<HID, false, false><<<gb, 512, 0, stream>>>(
      hA /*unused T2 slot*/ == nullptr ? hA : hB, rowptr, csr, csrw, dinv, W1t, b1,
      nullptr, nullptr, nullptr, nullptr, hA, N_NODES);

  // conv1 #2 + conv2 fused: agg(hA) -> GEMM W1 (+b1,relu) -> LDS -> GEMM W2a + gi2[batch] -> hB
  fused_kernel<HID, false, true><<<gb, 512, 0, stream>>>(
      hA, rowptr, csr, csrw, dinv, W1t, b1, W2at, gi2, batch, nullptr, hB, N_NODES);

  // conv2 agg + b2 + relu + dot(W3) -> t3
  agg_dot_kernel<<<(N_NODES + 7) / 8, 256, 0, stream>>>(hB, rowptr, csr, csrw, dinv, b2, W3, t3, N_NODES);

  // conv3 aggregation (scalar)
  final_kernel<<<(N_NODES + 255) / 256, 256, 0, stream>>>(t3, rowptr, csr, csrw, dinv, b3, out, N_NODES);
}